// Round 10
// baseline (3419.020 us; speedup 1.0000x reference)
//
#include <hip/hip_runtime.h>
#include <math.h>

#define NTHR  256
#define EGRID 4096   // grid-stride blocks for edge kernel

static __device__ __forceinline__ float sigf(float x) {
  return 1.0f / (1.0f + __expf(-x));
}
static __device__ __forceinline__ float tanhfast(float x) {
  return 2.0f / (1.0f + __expf(-2.0f * x)) - 1.0f;
}

// m = x @ conv_weight   (x:[N,4], w:[4,4] row-major, m:[N,4])
__global__ void conv_m_kernel(const float* __restrict__ x,
                              const float* __restrict__ w,
                              float* __restrict__ m, int n) {
  int i = blockIdx.x * blockDim.x + threadIdx.x;
  if (i >= n) return;
  float4 xv = reinterpret_cast<const float4*>(x)[i];
  float4 mv;
  mv.x = xv.x * w[0] + xv.y * w[4] + xv.z * w[8]  + xv.w * w[12];
  mv.y = xv.x * w[1] + xv.y * w[5] + xv.z * w[9]  + xv.w * w[13];
  mv.z = xv.x * w[2] + xv.y * w[6] + xv.z * w[10] + xv.w * w[14];
  mv.w = xv.x * w[3] + xv.y * w[7] + xv.z * w[11] + xv.w * w[15];
  reinterpret_cast<float4*>(m)[i] = mv;
}

// ---- single-pass aggregation: fire-and-forget global f32 atomics into
// L2-resident sumBuf/cntBuf. No LDS RMW, no binning, no return-wait.
__global__ __launch_bounds__(NTHR) void edge_atomic_kernel(
    const int* __restrict__ ei, const float* __restrict__ ew,
    const float* __restrict__ m,
    float* __restrict__ summed, float* __restrict__ cnt, int E) {
  const int4* s4 = reinterpret_cast<const int4*>(ei);
  const int4* d4 = reinterpret_cast<const int4*>(ei + E);
  const float4* w4 = reinterpret_cast<const float4*>(ew);
  const float4* m4 = reinterpret_cast<const float4*>(m);
  int lim4 = E >> 2;
  int stride = gridDim.x * blockDim.x;
  for (int i4 = blockIdx.x * blockDim.x + threadIdx.x; i4 < lim4; i4 += stride) {
    int4 s = s4[i4];
    int4 d = d4[i4];
    float4 w = w4[i4];
    // all 4 gathers issued before any atomic (ILP over L2 latency)
    float4 v0 = m4[s.x];
    float4 v1 = m4[s.y];
    float4 v2 = m4[s.z];
    float4 v3 = m4[s.w];
    float* p0 = summed + 4ll * d.x;
    float* p1 = summed + 4ll * d.y;
    float* p2 = summed + 4ll * d.z;
    float* p3 = summed + 4ll * d.w;
    unsafeAtomicAdd(p0 + 0, v0.x * w.x);
    unsafeAtomicAdd(p0 + 1, v0.y * w.x);
    unsafeAtomicAdd(p0 + 2, v0.z * w.x);
    unsafeAtomicAdd(p0 + 3, v0.w * w.x);
    unsafeAtomicAdd(cnt + d.x, 1.0f);
    unsafeAtomicAdd(p1 + 0, v1.x * w.y);
    unsafeAtomicAdd(p1 + 1, v1.y * w.y);
    unsafeAtomicAdd(p1 + 2, v1.z * w.y);
    unsafeAtomicAdd(p1 + 3, v1.w * w.y);
    unsafeAtomicAdd(cnt + d.y, 1.0f);
    unsafeAtomicAdd(p2 + 0, v2.x * w.z);
    unsafeAtomicAdd(p2 + 1, v2.y * w.z);
    unsafeAtomicAdd(p2 + 2, v2.z * w.z);
    unsafeAtomicAdd(p2 + 3, v2.w * w.z);
    unsafeAtomicAdd(cnt + d.z, 1.0f);
    unsafeAtomicAdd(p3 + 0, v3.x * w.w);
    unsafeAtomicAdd(p3 + 1, v3.y * w.w);
    unsafeAtomicAdd(p3 + 2, v3.z * w.w);
    unsafeAtomicAdd(p3 + 3, v3.w * w.w);
    unsafeAtomicAdd(cnt + d.w, 1.0f);
  }
  // tail (E not multiple of 4)
  if (blockIdx.x == 0 && threadIdx.x == 0) {
    for (int e = E & ~3; e < E; ++e) {
      int sE = ei[e], dE = ei[E + e];
      float wE = ew[e];
      float4 v = m4[sE];
      float* p = summed + 4ll * dE;
      unsafeAtomicAdd(p + 0, v.x * wE);
      unsafeAtomicAdd(p + 1, v.y * wE);
      unsafeAtomicAdd(p + 2, v.z * wE);
      unsafeAtomicAdd(p + 3, v.w * wE);
      unsafeAtomicAdd(cnt + dE, 1.0f);
    }
  }
}

// fused GRU+LSTM+head; weights staged in LDS; jc loop rolled
__global__ __launch_bounds__(NTHR) void node_kernel2(
    const float* __restrict__ x, const float* __restrict__ sumBuf,
    const float* __restrict__ cntBuf,
    const float* __restrict__ h0, const float* __restrict__ c0,
    const float* __restrict__ gwi, const float* __restrict__ gwh,
    const float* __restrict__ gbi, const float* __restrict__ gbh,
    const float* __restrict__ lwi, const float* __restrict__ lwh,
    const float* __restrict__ lbi, const float* __restrict__ lbh,
    const float* __restrict__ linw, const float* __restrict__ linb,
    float* __restrict__ out, float* __restrict__ hout, float* __restrict__ cout,
    int n) {
  __shared__ float4 s_lwh[1024];   // [j*8+q], j<128, q<8
  __shared__ float4 s_lwi[128];    // [j]
  __shared__ float  s_lb[128];     // lbi[j]+lbh[j]
  __shared__ float  s_linw[32];
  __shared__ float  s_gwi[48], s_gwh[48], s_gbi[12], s_gbh[12];

  int tid = threadIdx.x;
  for (int k = tid; k < 4096; k += NTHR) ((float*)s_lwh)[k] = lwh[k];
  for (int k = tid; k < 512; k += NTHR) ((float*)s_lwi)[k] = lwi[k];
  if (tid < 128) s_lb[tid] = lbi[tid] + lbh[tid];
  if (tid < 32) s_linw[tid] = linw[tid];
  if (tid < 48) { s_gwi[tid] = gwi[tid]; s_gwh[tid] = gwh[tid]; }
  if (tid < 12) { s_gbi[tid] = gbi[tid]; s_gbh[tid] = gbh[tid]; }
  __syncthreads();

  int i = blockIdx.x * blockDim.x + tid;
  if (i >= n) return;

  float4 sv = reinterpret_cast<const float4*>(sumBuf)[i];
  float inv = 1.0f / fmaxf(cntBuf[i], 1.0f);
  float agg[4] = {sv.x * inv, sv.y * inv, sv.z * inv, sv.w * inv};
  float4 xv = reinterpret_cast<const float4*>(x)[i];
  float xa[4] = {xv.x, xv.y, xv.z, xv.w};

  // ---- GRUCell (gate order r,z,n)
  float hc[4];
#pragma unroll
  for (int c = 0; c < 4; ++c) {
    float gi_r = s_gbi[c],     gh_r = s_gbh[c];
    float gi_z = s_gbi[4 + c], gh_z = s_gbh[4 + c];
    float gi_n = s_gbi[8 + c], gh_n = s_gbh[8 + c];
#pragma unroll
    for (int k = 0; k < 4; ++k) {
      gi_r += agg[k] * s_gwi[c * 4 + k];       gh_r += xa[k] * s_gwh[c * 4 + k];
      gi_z += agg[k] * s_gwi[(4 + c) * 4 + k]; gh_z += xa[k] * s_gwh[(4 + c) * 4 + k];
      gi_n += agg[k] * s_gwi[(8 + c) * 4 + k]; gh_n += xa[k] * s_gwh[(8 + c) * 4 + k];
    }
    float r = sigf(gi_r + gh_r);
    float z = sigf(gi_z + gh_z);
    float nn = tanhfast(gi_n + r * gh_n);
    hc[c] = (1.0f - z) * nn + z * xa[c];
  }

  // ---- LSTM single step (gate order i,f,g,o)
  const float4* h04 = reinterpret_cast<const float4*>(h0) + (size_t)i * 8;
  const float4* c04 = reinterpret_cast<const float4*>(c0) + (size_t)i * 8;
  float hp[32];
#pragma unroll
  for (int q = 0; q < 8; ++q) {
    float4 hv = h04[q];
    hp[q * 4 + 0] = hv.x; hp[q * 4 + 1] = hv.y;
    hp[q * 4 + 2] = hv.z; hp[q * 4 + 3] = hv.w;
  }
  float oacc = linb[0];
  float4* hout4 = reinterpret_cast<float4*>(hout) + (size_t)i * 8;
  float4* cout4 = reinterpret_cast<float4*>(cout) + (size_t)i * 8;

#pragma unroll 1
  for (int jc = 0; jc < 8; ++jc) {
    float4 cpv = c04[jc];
    float cpa[4] = {cpv.x, cpv.y, cpv.z, cpv.w};
    float hn[4], cn[4];
#pragma unroll
    for (int jj = 0; jj < 4; ++jj) {
      int j = jc * 4 + jj;
      float gI = s_lb[j];
      float gF = s_lb[32 + j];
      float gG = s_lb[64 + j];
      float gO = s_lb[96 + j];
      float4 wi = s_lwi[j], wf = s_lwi[32 + j], wg = s_lwi[64 + j], wo = s_lwi[96 + j];
      gI += hc[0] * wi.x + hc[1] * wi.y + hc[2] * wi.z + hc[3] * wi.w;
      gF += hc[0] * wf.x + hc[1] * wf.y + hc[2] * wf.z + hc[3] * wf.w;
      gG += hc[0] * wg.x + hc[1] * wg.y + hc[2] * wg.z + hc[3] * wg.w;
      gO += hc[0] * wo.x + hc[1] * wo.y + hc[2] * wo.z + hc[3] * wo.w;
#pragma unroll
      for (int q = 0; q < 8; ++q) {
        float4 a = s_lwh[j * 8 + q];
        float4 b = s_lwh[(32 + j) * 8 + q];
        float4 g = s_lwh[(64 + j) * 8 + q];
        float4 o = s_lwh[(96 + j) * 8 + q];
        float p0 = hp[q * 4 + 0], p1 = hp[q * 4 + 1];
        float p2 = hp[q * 4 + 2], p3 = hp[q * 4 + 3];
        gI += p0 * a.x + p1 * a.y + p2 * a.z + p3 * a.w;
        gF += p0 * b.x + p1 * b.y + p2 * b.z + p3 * b.w;
        gG += p0 * g.x + p1 * g.y + p2 * g.z + p3 * g.w;
        gO += p0 * o.x + p1 * o.y + p2 * o.z + p3 * o.w;
      }
      float ig = sigf(gI), fg = sigf(gF), og = sigf(gO), gg = tanhfast(gG);
      float cnew = fg * cpa[jj] + ig * gg;
      float hnew = og * tanhfast(cnew);
      cn[jj] = cnew; hn[jj] = hnew;
      oacc += fmaxf(hnew, 0.0f) * s_linw[j];
    }
    hout4[jc] = make_float4(hn[0], hn[1], hn[2], hn[3]);
    cout4[jc] = make_float4(cn[0], cn[1], cn[2], cn[3]);
  }
  out[i] = oacc;
}

extern "C" void kernel_launch(void* const* d_in, const int* in_sizes, int n_in,
                              void* d_out, int out_size, void* d_ws, size_t ws_size,
                              hipStream_t stream) {
  const float* x     = (const float*)d_in[0];
  const int*   ei    = (const int*)d_in[1];
  const float* ew    = (const float*)d_in[2];
  const float* h0    = (const float*)d_in[3];
  const float* c0    = (const float*)d_in[4];
  const float* convw = (const float*)d_in[5];
  const float* gwi   = (const float*)d_in[6];
  const float* gwh   = (const float*)d_in[7];
  const float* gbi   = (const float*)d_in[8];
  const float* gbh   = (const float*)d_in[9];
  const float* lwi   = (const float*)d_in[10];
  const float* lwh   = (const float*)d_in[11];
  const float* lbi   = (const float*)d_in[12];
  const float* lbh   = (const float*)d_in[13];
  const float* linw  = (const float*)d_in[14];
  const float* linb  = (const float*)d_in[15];

  int n = in_sizes[0] / 4;   // N nodes
  int E = in_sizes[1] / 2;   // edges

  float* out  = (float*)d_out;
  float* hout = out + n;
  float* cout = hout + (size_t)n * 32;

  // workspace: m[N*4] | summed[N*4] | cnt[N]
  float* m      = (float*)d_ws;
  float* summed = m + (size_t)n * 4;
  float* cntp   = summed + (size_t)n * 4;

  hipMemsetAsync(summed, 0, (size_t)n * 5 * sizeof(float), stream);
  conv_m_kernel<<<(n + NTHR - 1) / NTHR, NTHR, 0, stream>>>(x, convw, m, n);

  int e4 = E >> 2;
  int eb = (e4 + NTHR - 1) / NTHR;
  if (eb > EGRID) eb = EGRID;
  edge_atomic_kernel<<<eb, NTHR, 0, stream>>>(ei, ew, m, summed, cntp, E);

  node_kernel2<<<(n + NTHR - 1) / NTHR, NTHR, 0, stream>>>(
      x, summed, cntp, h0, c0,
      gwi, gwh, gbi, gbh, lwi, lwh, lbi, lbh, linw, linb,
      out, hout, cout, n);
}